// Round 1
// baseline (191.201 us; speedup 1.0000x reference)
//
#include <hip/hip_runtime.h>

#define TPTS 100   // points per voxel (T)
#define CF   9     // derived feature channels
#define CO   64    // output channels
#define KK   8     // k-NN

__global__ __launch_bounds__(256) void dgcnn_kernel(
    const float* __restrict__ features,   // [V][100][4]
    const float* __restrict__ conv_w,     // [64][18]
    const float* __restrict__ bn_gamma,
    const float* __restrict__ bn_beta,
    const float* __restrict__ bn_mean,
    const float* __restrict__ bn_var,
    const int*  __restrict__ num_voxels,  // [V]
    const int*  __restrict__ coors,       // [V][4]
    float* __restrict__ out)              // [V][64]
{
    __shared__ float s_feat[TPTS][CF];    // 3600 B
    __shared__ float s_xx[TPTS];          // 400 B
    __shared__ int   s_idx[TPTS][KK];     // 3200 B
    __shared__ float s_w[CO * 18];        // 4608 B
    __shared__ float s_redmax[4][CO];     // 1024 B
    __shared__ float s_redmin[4][CO];     // 1024 B
    __shared__ float s_mean[3];
    __shared__ union {                    // 25600 B (time-shared)
        float stage[TPTS][4];             // raw features (phases A/B)
        float g[TPTS][CO];                // g[s][o] (phases E/F)
    } s_u;

    const float NEG_INF = -__builtin_inff();
    const int v   = blockIdx.x;
    const int tid = threadIdx.x;
    const int nv  = num_voxels[v];

    // ---- Phase A: stage conv_w and raw features ----
    for (int i = tid; i < CO * 18; i += 256) s_w[i] = conv_w[i];

    float4 f = make_float4(0.f, 0.f, 0.f, 0.f);
    if (tid < TPTS) {
        f = reinterpret_cast<const float4*>(features)[v * TPTS + tid];
        s_u.stage[tid][0] = f.x;
        s_u.stage[tid][1] = f.y;
        s_u.stage[tid][2] = f.z;
    }
    __syncthreads();

    // ---- Phase B: mean of ch 0..2 over ALL 100 rows, / nv ----
    if (tid < 96) {
        int ch = tid >> 5, j = tid & 31;
        float p = s_u.stage[j][ch] + s_u.stage[j + 32][ch] + s_u.stage[j + 64][ch];
        if (j < 4) p += s_u.stage[j + 96][ch];
        #pragma unroll
        for (int off = 16; off >= 1; off >>= 1)
            p += __shfl_xor(p, off, 32);
        if (j == 0) s_mean[ch] = p / (float)nv;
    }
    __syncthreads();

    // ---- Phase C: build masked feat[100][9] and xx[100] ----
    if (tid < TPTS) {
        float mask = (tid < nv) ? 1.0f : 0.0f;
        float c3 = (float)coors[v * 4 + 3];
        float c2 = (float)coors[v * 4 + 2];
        float r[CF];
        r[0] = f.x; r[1] = f.y; r[2] = f.z; r[3] = f.w;
        r[4] = f.x - s_mean[0];
        r[5] = f.y - s_mean[1];
        r[6] = f.z - s_mean[2];
        r[7] = f.x - (c3 * 0.2f + 0.1f);    // VX, X_OFF
        r[8] = f.y - (c2 * 0.2f - 39.9f);   // VY, Y_OFF
        float xx = 0.f;
        #pragma unroll
        for (int c = 0; c < CF; ++c) {
            r[c] *= mask;
            s_feat[tid][c] = r[c];
            xx += r[c] * r[c];
        }
        s_xx[tid] = xx;
    }
    __syncthreads();

    // ---- Phase D: per-row top-8 neighbors (threads 0..99) ----
    {
        int wbase = tid & ~63;                 // wave-uniform
        if (tid < 128 && wbase < nv) {         // skip wave 1 when nv <= 64
            int t = (tid < TPTS) ? tid : (TPTS - 1);
            float ft[CF];
            #pragma unroll
            for (int c = 0; c < CF; ++c) ft[c] = s_feat[t][c];
            float xt = s_xx[t];
            float val[KK]; int vidx[KK];
            #pragma unroll
            for (int k = 0; k < KK; ++k) { val[k] = NEG_INF; vidx[k] = 0; }
            for (int s = 0; s < TPTS; ++s) {
                float dot = 0.f;
                #pragma unroll
                for (int c = 0; c < CF; ++c) dot += ft[c] * s_feat[s][c];
                float d = 2.0f * dot - xt - s_xx[s];
                // stable insertion: new elem displaces only on strictly-greater,
                // displaced elems shift unconditionally (ins flag)
                float cv = d; int ci = s; bool ins = false;
                #pragma unroll
                for (int k = 0; k < KK; ++k) {
                    bool sw = ins || (cv > val[k]);
                    float tv = val[k]; int ti = vidx[k];
                    val[k]  = sw ? cv : tv;
                    vidx[k] = sw ? ci : ti;
                    cv = sw ? tv : cv;
                    ci = sw ? ti : ci;
                    ins = sw;
                }
            }
            if (tid < TPTS) {
                #pragma unroll
                for (int k = 0; k < KK; ++k) s_idx[t][k] = vidx[k];
            }
        }
    }
    __syncthreads();

    // ---- Phase E: g[s][o] = sum_c feat[s][c] * W1[o][c] ----
    const int o = tid & 63;
    const int w = tid >> 6;
    float w1[CF], w2[CF];
    #pragma unroll
    for (int c = 0; c < CF; ++c) {
        float a = s_w[o * 18 + c];
        float b = s_w[o * 18 + 9 + c];
        w1[c] = a;
        w2[c] = b - a;                    // base uses (W[:,9+c] - W[:,c])
    }
    for (int j = 0; j < 25; ++j) {
        int s = w * 25 + j;               // wave-uniform s -> broadcast reads
        float acc = 0.f;
        #pragma unroll
        for (int c = 0; c < CF; ++c) acc += s_feat[s][c] * w1[c];
        s_u.g[s][o] = acc;                // lane-consecutive -> conflict-free
    }
    __syncthreads();

    // ---- Phase F: M[o] = max/min over valid (t,k) of g[nbr][o]+base[t][o] ----
    float Mmax = NEG_INF, Mmin = -NEG_INF;
    {
        int tlo  = w * 25;
        int tcnt = nv - tlo; if (tcnt > 25) tcnt = 25;   // wave-uniform
        for (int j = 0; j < tcnt; ++j) {
            int t = tlo + j;
            float base = 0.f;
            #pragma unroll
            for (int c = 0; c < CF; ++c) base += s_feat[t][c] * w2[c];
            #pragma unroll
            for (int k = 0; k < KK; ++k) {
                int s = s_idx[t][k];
                float hv = s_u.g[s][o] + base;
                Mmax = fmaxf(Mmax, hv);
                Mmin = fminf(Mmin, hv);
            }
        }
    }
    s_redmax[w][o] = Mmax;
    s_redmin[w][o] = Mmin;
    __syncthreads();

    // ---- Phase G: cross-wave reduce, BN + leakyReLU + mask-max, store ----
    if (tid < CO) {
        float mx = fmaxf(fmaxf(s_redmax[0][tid], s_redmax[1][tid]),
                         fmaxf(s_redmax[2][tid], s_redmax[3][tid]));
        float mn = fminf(fminf(s_redmin[0][tid], s_redmin[1][tid]),
                         fminf(s_redmin[2][tid], s_redmin[3][tid]));
        float scale = bn_gamma[tid] / sqrtf(bn_var[tid] + 0.001f);
        float bias  = bn_beta[tid] - bn_mean[tid] * scale;
        float m = (scale >= 0.f) ? mx : mn;   // activation monotonicity dir
        float h = m * scale + bias;
        float a = (h > 0.f) ? h : 0.2f * h;   // leaky_relu
        if (nv < TPTS) a = fmaxf(a, 0.f);     // masked rows contribute 0
        out[v * CO + tid] = a;
    }
}

extern "C" void kernel_launch(void* const* d_in, const int* in_sizes, int n_in,
                              void* d_out, int out_size, void* d_ws, size_t ws_size,
                              hipStream_t stream) {
    const float* features = (const float*)d_in[0];
    const float* conv_w   = (const float*)d_in[1];
    const float* bn_gamma = (const float*)d_in[2];
    const float* bn_beta  = (const float*)d_in[3];
    const float* bn_mean  = (const float*)d_in[4];
    const float* bn_var   = (const float*)d_in[5];
    const int*   num_vox  = (const int*)d_in[6];
    const int*   coor     = (const int*)d_in[7];
    float* outp = (float*)d_out;
    const int V = in_sizes[6];   // 4096 voxels
    dgcnn_kernel<<<V, 256, 0, stream>>>(features, conv_w, bn_gamma, bn_beta,
                                        bn_mean, bn_var, num_vox, coor, outp);
}

// Round 2
// 151.963 us; speedup vs baseline: 1.2582x; 1.2582x over previous
//
#include <hip/hip_runtime.h>

#define TPTS 100   // points per voxel (T)
#define CO   64    // output channels
#define KK   8     // k-NN

// Key algebra: the 9-dim edge feature is an affine image of the raw 4-dim
// point p=(x,y,z,w): ch4-6 = p3 - mean, ch7-8 = (x,y) - voxel center.
// In d(t,s) = 2<f_t,f_s> - |f_t|^2 - |f_s|^2 every affine offset cancels,
// leaving d = -(3dx^2 + 3dy^2 + 2dz^2 + dw^2)  (valid rows).
// Masked columns (s>=nv, f_s = 0) give d = -|f_t|^2, identical for all such s.
__global__ __launch_bounds__(256) void dgcnn_kernel(
    const float* __restrict__ features,   // [V][100][4]
    const float* __restrict__ conv_w,     // [64][18]
    const float* __restrict__ bn_gamma,
    const float* __restrict__ bn_beta,
    const float* __restrict__ bn_mean,
    const float* __restrict__ bn_var,
    const int*  __restrict__ num_voxels,  // [V]
    const int*  __restrict__ coors,       // [V][4]
    float* __restrict__ out)              // [V][64]
{
    __shared__ float4 s_q[TPTS];          // 1600 B scaled masked coords
    __shared__ float  s_feat[TPTS][12];   // 4800 B masked 9-dim feat (padded)
    __shared__ float  s_xx[TPTS];         //  400 B |feat|^2
    __shared__ int    s_idx[TPTS][12];    // 4800 B top-8 idx (slot 8 = dump)
    __shared__ float  s_red[4][CO];       // 1024 B
    __shared__ float  s_mean[4];
    __shared__ union {                    // 25600 B (time-shared)
        float stage[TPTS][4];             // raw features (A/B)
        float g[TPTS][CO];                // g[s][o] (E/F)
    } s_u;

    const float INF = __builtin_inff();
    const int v   = blockIdx.x;
    const int tid = threadIdx.x;
    const int nv  = num_voxels[v];

    // ---- Phase A: stage raw features ----
    float4 f = make_float4(0.f, 0.f, 0.f, 0.f);
    if (tid < TPTS) {
        f = reinterpret_cast<const float4*>(features)[v * TPTS + tid];
        *reinterpret_cast<float4*>(&s_u.stage[tid][0]) = f;
    }
    __syncthreads();

    // ---- Phase B: mean of ch 0..2 over ALL 100 raw rows, / nv ----
    if (tid < 96) {
        int ch = tid >> 5, j = tid & 31;
        float p = s_u.stage[j][ch] + s_u.stage[j + 32][ch] + s_u.stage[j + 64][ch];
        if (j < 4) p += s_u.stage[j + 96][ch];
        #pragma unroll
        for (int off = 16; off >= 1; off >>= 1)
            p += __shfl_xor(p, off, 32);
        if (j == 0) s_mean[ch] = p / (float)nv;
    }
    __syncthreads();

    // ---- Phase C: build masked feat[100][9], xx, scaled q ----
    if (tid < TPTS) {
        float mask = (tid < nv) ? 1.0f : 0.0f;
        float c3 = (float)coors[v * 4 + 3];
        float c2 = (float)coors[v * 4 + 2];
        float r[12];
        r[0] = f.x; r[1] = f.y; r[2] = f.z; r[3] = f.w;
        r[4] = f.x - s_mean[0];
        r[5] = f.y - s_mean[1];
        r[6] = f.z - s_mean[2];
        r[7] = f.x - (c3 * 0.2f + 0.1f);    // VX, X_OFF
        r[8] = f.y - (c2 * 0.2f - 39.9f);   // VY, Y_OFF
        r[9] = r[10] = r[11] = 0.f;
        float xx = 0.f;
        #pragma unroll
        for (int c = 0; c < 9; ++c) { r[c] *= mask; xx += r[c] * r[c]; }
        float4* rowv = reinterpret_cast<float4*>(&s_feat[tid][0]);
        rowv[0] = make_float4(r[0], r[1], r[2], r[3]);
        rowv[1] = make_float4(r[4], r[5], r[6], r[7]);
        rowv[2] = make_float4(r[8], 0.f, 0.f, 0.f);
        s_xx[tid] = xx;
        s_q[tid] = make_float4(1.7320508075688772f * r[0],
                               1.7320508075688772f * r[1],
                               1.4142135623730951f * r[2],
                               r[3]);
        #pragma unroll
        for (int k = 0; k < KK; ++k) s_idx[tid][k] = 0;  // graceful-fail prefill
    }
    __syncthreads();

    // ---- Phase D: per-row top-8 (smallest e), threads 0..99 ----
    {
        int wbase = tid & ~63;                 // wave-uniform
        if (tid < 128 && wbase < nv) {
            int t = (tid < TPTS) ? tid : (TPTS - 1);
            float4 qt = s_q[t];
            float e_msk = s_xx[t];             // e of every masked column
            float val[KK];
            #pragma unroll
            for (int k = 0; k < KK; ++k) val[k] = INF;
            // pass 1: value-only 8-smallest over valid s
            for (int s = 0; s < nv; ++s) {
                float4 qs = s_q[s];
                float dx = qt.x - qs.x, dy = qt.y - qs.y;
                float dz = qt.z - qs.z, dw = qt.w - qs.w;
                float e = __fmaf_rn(dx, dx, __fmaf_rn(dy, dy,
                          __fmaf_rn(dz, dz, dw * dw)));
                float cv = e;
                #pragma unroll
                for (int k = 0; k < KK; ++k) {
                    float lo = fminf(val[k], cv);
                    cv = fmaxf(val[k], cv);
                    val[k] = lo;
                }
            }
            int mcnt = TPTS - nv; if (mcnt > KK) mcnt = KK;  // uniform
            for (int j = 0; j < mcnt; ++j) {                  // masked copies
                float cv = e_msk;
                #pragma unroll
                for (int k = 0; k < KK; ++k) {
                    float lo = fminf(val[k], cv);
                    cv = fmaxf(val[k], cv);
                    val[k] = lo;
                }
            }
            float thr = val[KK - 1];           // 8th smallest (finite)
            // pass 2: stable index collection.
            // lt's fill slots bottom-up; eq #j goes to slot 7-j when it
            // cannot collide with an already-written lt (eslot >= cnt_lt);
            // over-quota eq's are either dumped or later overwritten by
            // their slot's lt. Exact-recompute via __fmaf_rn guarantees
            // pass2 e is bit-identical to pass1.
            int cnt_lt = 0, cnt_eq = 0;
            for (int s = 0; s < nv; ++s) {
                float4 qs = s_q[s];
                float dx = qt.x - qs.x, dy = qt.y - qs.y;
                float dz = qt.z - qs.z, dw = qt.w - qs.w;
                float e = __fmaf_rn(dx, dx, __fmaf_rn(dy, dy,
                          __fmaf_rn(dz, dz, dw * dw)));
                bool lt = e < thr;
                bool eq = (e == thr);
                int eslot = (KK - 1) - cnt_eq;
                bool eok = eq && (cnt_eq < KK) && (eslot >= cnt_lt);
                int slot = lt ? cnt_lt : (eok ? eslot : KK);   // KK = dump
                s_idx[t][slot] = s;
                cnt_lt += lt ? 1 : 0;
                cnt_eq += eq ? 1 : 0;
            }
            {   // masked columns: indices nv, nv+1, ... (ascending = stable)
                bool lt = e_msk < thr;
                bool eq = (e_msk == thr);
                for (int j = 0; j < mcnt; ++j) {
                    int eslot = (KK - 1) - cnt_eq;
                    bool eok = eq && (cnt_eq < KK) && (eslot >= cnt_lt);
                    int slot = lt ? cnt_lt : (eok ? eslot : KK);
                    s_idx[t][slot] = nv + j;
                    cnt_lt += lt ? 1 : 0;
                    cnt_eq += eq ? 1 : 0;
                }
            }
        }
    }
    __syncthreads();

    // ---- Phase E: g[s][o] = sgn_o * <feat_s, W1_o> ----
    const int o = tid & 63;
    const int w = tid >> 6;
    const float sgn = (bn_gamma[o] < 0.f) ? -1.f : 1.f;  // fold activation dir
    float w1[9], w2[9];
    #pragma unroll
    for (int c = 0; c < 9; ++c) {
        float a = conv_w[o * 18 + c];
        float b = conv_w[o * 18 + 9 + c];
        w1[c] = a * sgn;
        w2[c] = (b - a) * sgn;
    }
    for (int j = 0; j < 25; ++j) {
        int s = w * 25 + j;               // wave-uniform -> broadcast reads
        const float4* row = reinterpret_cast<const float4*>(&s_feat[s][0]);
        float4 r0 = row[0], r1 = row[1], r2 = row[2];
        float acc = r0.x * w1[0] + r0.y * w1[1] + r0.z * w1[2] + r0.w * w1[3]
                  + r1.x * w1[4] + r1.y * w1[5] + r1.z * w1[6] + r1.w * w1[7]
                  + r2.x * w1[8];
        s_u.g[s][o] = acc;                // lane-consecutive -> conflict-free
    }
    __syncthreads();

    // ---- Phase F: acc[o] = max over valid (t,k) of sgn*(g[nbr]+base) ----
    float acc = -INF;
    {
        int tlo  = w * 25;
        int tcnt = nv - tlo; if (tcnt > 25) tcnt = 25;   // wave-uniform
        for (int j = 0; j < tcnt; ++j) {
            int t = tlo + j;
            const float4* row = reinterpret_cast<const float4*>(&s_feat[t][0]);
            float4 r0 = row[0], r1 = row[1], r2 = row[2];
            float base = r0.x * w2[0] + r0.y * w2[1] + r0.z * w2[2] + r0.w * w2[3]
                       + r1.x * w2[4] + r1.y * w2[5] + r1.z * w2[6] + r1.w * w2[7]
                       + r2.x * w2[8];
            const int4* ip = reinterpret_cast<const int4*>(&s_idx[t][0]);
            int4 i0 = ip[0], i1 = ip[1];
            acc = fmaxf(acc, s_u.g[i0.x][o] + base);
            acc = fmaxf(acc, s_u.g[i0.y][o] + base);
            acc = fmaxf(acc, s_u.g[i0.z][o] + base);
            acc = fmaxf(acc, s_u.g[i0.w][o] + base);
            acc = fmaxf(acc, s_u.g[i1.x][o] + base);
            acc = fmaxf(acc, s_u.g[i1.y][o] + base);
            acc = fmaxf(acc, s_u.g[i1.z][o] + base);
            acc = fmaxf(acc, s_u.g[i1.w][o] + base);
        }
    }
    s_red[w][o] = acc;
    __syncthreads();

    // ---- Phase G: cross-wave reduce, BN + leakyReLU + mask-max, store ----
    if (tid < CO) {
        float m = fmaxf(fmaxf(s_red[0][tid], s_red[1][tid]),
                        fmaxf(s_red[2][tid], s_red[3][tid]));
        float scale = bn_gamma[tid] / sqrtf(bn_var[tid] + 0.001f);
        float bias  = bn_beta[tid] - bn_mean[tid] * scale;
        float h = m * fabsf(scale) + bias;    // m tracks sgn*h_pre
        float a = (h > 0.f) ? h : 0.2f * h;   // leaky_relu
        if (nv < TPTS) a = fmaxf(a, 0.f);     // masked rows contribute 0
        out[v * CO + tid] = a;
    }
}

extern "C" void kernel_launch(void* const* d_in, const int* in_sizes, int n_in,
                              void* d_out, int out_size, void* d_ws, size_t ws_size,
                              hipStream_t stream) {
    const float* features = (const float*)d_in[0];
    const float* conv_w   = (const float*)d_in[1];
    const float* bn_gamma = (const float*)d_in[2];
    const float* bn_beta  = (const float*)d_in[3];
    const float* bn_mean  = (const float*)d_in[4];
    const float* bn_var   = (const float*)d_in[5];
    const int*   num_vox  = (const int*)d_in[6];
    const int*   coor     = (const int*)d_in[7];
    float* outp = (float*)d_out;
    const int V = in_sizes[6];   // 4096 voxels
    dgcnn_kernel<<<V, 256, 0, stream>>>(features, conv_w, bn_gamma, bn_beta,
                                        bn_mean, bn_var, num_vox, coor, outp);
}

// Round 4
// 124.112 us; speedup vs baseline: 1.5406x; 1.2244x over previous
//
#include <hip/hip_runtime.h>

#define TPTS 100   // points per voxel (T)
#define CO   64    // output channels
#define KK   8     // k-NN

// Distances: the 9-dim edge feature is an affine image of the raw point
// (x,y,z,w), so |f_t - f_s|^2 = 3dx^2 + 3dy^2 + 2dz^2 + dw^2 for valid
// rows; masked columns (f_s = 0) give e = |f_t|^2 (9-dim norm, s_xx).
// Top-8 selection uses packed keys: (as_uint(e) & ~0x7F) | s  -- uint
// order == float order (e >= 0), ties break by lowest index, one pass.
__device__ __forceinline__ unsigned umin_(unsigned a, unsigned b) { return a < b ? a : b; }
__device__ __forceinline__ unsigned umax_(unsigned a, unsigned b) { return a > b ? a : b; }

__device__ __forceinline__ unsigned dist_key(const float4 qt, const float4 qs, unsigned s) {
    float dx = qt.x - qs.x, dy = qt.y - qs.y;
    float dz = qt.z - qs.z, dw = qt.w - qs.w;
    float e = __fmaf_rn(dx, dx, __fmaf_rn(dy, dy, __fmaf_rn(dz, dz, dw * dw)));
    return (__float_as_uint(e) & 0xFFFFFF80u) | s;
}

__global__ __launch_bounds__(256) void dgcnn_kernel(
    const float* __restrict__ features,   // [V][100][4]
    const float* __restrict__ conv_w,     // [64][18]
    const float* __restrict__ bn_gamma,
    const float* __restrict__ bn_beta,
    const float* __restrict__ bn_mean,
    const float* __restrict__ bn_var,
    const int*  __restrict__ num_voxels,  // [V]
    const int*  __restrict__ coors,       // [V][4]
    float* __restrict__ out)              // [V][64]
{
    // rows: [0..3] = scaled coords q=(sqrt3*x, sqrt3*y, sqrt2*z, w) [masked],
    //       [4..8] = f_cluster/f_center channels [masked]; scale is folded
    //       into the conv weights (w1/w2 multiplied by 1/scale).
    __shared__ float s_feat[TPTS][12];    // 4800 B
    __shared__ float s_xx[TPTS];          //  400 B  9-dim |feat|^2
    __shared__ int   s_idx[KK][TPTS];     // 3200 B  transposed: lane-consec writes
    __shared__ float s_red[4][CO];        // 1024 B
    __shared__ float s_mean[4];
    __shared__ union {                    // 25600 B (time-shared)
        float stage[TPTS][4];             // raw features (A/B)
        float g[TPTS][CO];                // g[s][o] (E/F)
    } s_u;

    const float INF = __builtin_inff();
    const int v   = blockIdx.x;
    const int tid = threadIdx.x;
    const int nv  = num_voxels[v];

    // ---- Phase A: stage raw features ----
    float4 f = make_float4(0.f, 0.f, 0.f, 0.f);
    if (tid < TPTS) {
        f = reinterpret_cast<const float4*>(features)[v * TPTS + tid];
        *reinterpret_cast<float4*>(&s_u.stage[tid][0]) = f;
    }
    __syncthreads();

    // ---- Phase B: mean of ch 0..2 over ALL 100 raw rows, / nv ----
    if (tid < 96) {
        int ch = tid >> 5, j = tid & 31;
        float p = s_u.stage[j][ch] + s_u.stage[j + 32][ch] + s_u.stage[j + 64][ch];
        if (j < 4) p += s_u.stage[j + 96][ch];
        #pragma unroll
        for (int off = 16; off >= 1; off >>= 1)
            p += __shfl_xor(p, off, 32);
        if (j == 0) s_mean[ch] = p / (float)nv;
    }
    __syncthreads();

    // ---- Phase C: build masked feat rows (scaled coords inline) + xx ----
    if (tid < TPTS) {
        float mask = (tid < nv) ? 1.0f : 0.0f;
        float c3 = (float)coors[v * 4 + 3];
        float c2 = (float)coors[v * 4 + 2];
        float r0 = f.x * mask, r1 = f.y * mask, r2 = f.z * mask, r3 = f.w * mask;
        float r4 = (f.x - s_mean[0]) * mask;
        float r5 = (f.y - s_mean[1]) * mask;
        float r6 = (f.z - s_mean[2]) * mask;
        float r7 = (f.x - (c3 * 0.2f + 0.1f)) * mask;    // VX, X_OFF
        float r8 = (f.y - (c2 * 0.2f - 39.9f)) * mask;   // VY, Y_OFF
        float xx = r0*r0 + r1*r1 + r2*r2 + r3*r3 + r4*r4
                 + r5*r5 + r6*r6 + r7*r7 + r8*r8;
        float4* rowv = reinterpret_cast<float4*>(&s_feat[tid][0]);
        rowv[0] = make_float4(1.7320508075688772f * r0,
                              1.7320508075688772f * r1,
                              1.4142135623730951f * r2, r3);
        rowv[1] = make_float4(r4, r5, r6, r7);
        rowv[2] = make_float4(r8, 0.f, 0.f, 0.f);
        s_xx[tid] = xx;
    }
    __syncthreads();

    const int o = tid & 63;
    const int w = tid >> 6;
    const float sgn = (bn_gamma[o] < 0.f) ? -1.f : 1.f;  // fold activation dir
    float w2[9];

    if (tid < 128) {
        // ---- Phase D (waves 0,1): one-pass top-8 for valid rows ----
        const int t = tid;
        if (t < nv) {    // wave 1 fully skips when nv <= 64
            const float4 qt = *reinterpret_cast<const float4*>(&s_feat[t][0]);
            unsigned va[KK], vb[KK];
            #pragma unroll
            for (int k = 0; k < KK; ++k) { va[k] = 0xFFFFFFFFu; vb[k] = 0xFFFFFFFFu; }
            int s = 0;
            for (; s + 1 < nv; s += 2) {   // dual independent chains
                const float4 qa = *reinterpret_cast<const float4*>(&s_feat[s][0]);
                const float4 qb = *reinterpret_cast<const float4*>(&s_feat[s + 1][0]);
                unsigned ka = dist_key(qt, qa, (unsigned)s);
                unsigned kb = dist_key(qt, qb, (unsigned)(s + 1));
                #pragma unroll
                for (int k = 0; k < KK; ++k) {
                    unsigned la = umin_(va[k], ka); ka = umax_(va[k], ka); va[k] = la;
                    unsigned lb = umin_(vb[k], kb); kb = umax_(vb[k], kb); vb[k] = lb;
                }
            }
            if (s < nv) {                  // odd tail
                const float4 qa = *reinterpret_cast<const float4*>(&s_feat[s][0]);
                unsigned ka = dist_key(qt, qa, (unsigned)s);
                #pragma unroll
                for (int k = 0; k < KK; ++k) {
                    unsigned la = umin_(va[k], ka); ka = umax_(va[k], ka); va[k] = la;
                }
            }
            {   // masked columns: e = |f_t|^2, indices nv, nv+1, ... (<=8 needed)
                int mcnt = TPTS - nv; if (mcnt > KK) mcnt = KK;
                unsigned kmb = __float_as_uint(s_xx[t]) & 0xFFFFFF80u;
                for (int j = 0; j < mcnt; ++j) {
                    unsigned km = kmb | (unsigned)(nv + j);
                    if (j & 1) {
                        #pragma unroll
                        for (int k = 0; k < KK; ++k) {
                            unsigned lb = umin_(vb[k], km); km = umax_(vb[k], km); vb[k] = lb;
                        }
                    } else {
                        #pragma unroll
                        for (int k = 0; k < KK; ++k) {
                            unsigned la = umin_(va[k], km); km = umax_(va[k], km); va[k] = la;
                        }
                    }
                }
            }
            // bitonic half-clean merge: the 8 smallest of the union (unsorted ok)
            #pragma unroll
            for (int k = 0; k < KK; ++k) {
                unsigned key = umin_(va[k], vb[KK - 1 - k]);
                s_idx[k][t] = (int)(key & 127u);   // lane-consec: conflict-free
            }
        }
        // epilogue weights for F (scale-compensated, sign-folded)
        #pragma unroll
        for (int c = 0; c < 9; ++c) {
            const float ws = (c == 0 || c == 1) ? 0.57735026918962576f
                           : (c == 2) ? 0.70710678118654752f : 1.f;
            float a = conv_w[o * 18 + c];
            float b = conv_w[o * 18 + 9 + c];
            w2[c] = (b - a) * sgn * ws;
        }
    } else {
        // ---- Phase E (waves 2,3): g[s][o] = sgn * <feat_s, W1_o> ----
        float w1[9];
        #pragma unroll
        for (int c = 0; c < 9; ++c) {
            const float ws = (c == 0 || c == 1) ? 0.57735026918962576f
                           : (c == 2) ? 0.70710678118654752f : 1.f;
            float a = conv_w[o * 18 + c];
            float b = conv_w[o * 18 + 9 + c];
            w1[c] = a * sgn * ws;
            w2[c] = (b - a) * sgn * ws;
        }
        const int half = w - 2;
        for (int j = 0; j < 50; ++j) {
            int sR = half * 50 + j;       // wave-uniform -> broadcast reads
            const float4* row = reinterpret_cast<const float4*>(&s_feat[sR][0]);
            float4 a = row[0], b = row[1];
            float c8 = s_feat[sR][8];
            float g = a.x * w1[0];
            g = __fmaf_rn(a.y, w1[1], g);
            g = __fmaf_rn(a.z, w1[2], g);
            g = __fmaf_rn(a.w, w1[3], g);
            g = __fmaf_rn(b.x, w1[4], g);
            g = __fmaf_rn(b.y, w1[5], g);
            g = __fmaf_rn(b.z, w1[6], g);
            g = __fmaf_rn(b.w, w1[7], g);
            g = __fmaf_rn(c8,  w1[8], g);
            s_u.g[sR][o] = g;             // lane-consecutive -> conflict-free
        }
    }
    __syncthreads();

    // ---- Phase F: acc[o] = max over valid t of (max_k g[idx]) + base[t] ----
    float acc = -INF;
    for (int t = w; t < nv; t += 4) {     // interleaved: balanced across waves
        const float4* row = reinterpret_cast<const float4*>(&s_feat[t][0]);
        float4 a = row[0], b = row[1];
        float c8 = s_feat[t][8];
        float base = a.x * w2[0];
        base = __fmaf_rn(a.y, w2[1], base);
        base = __fmaf_rn(a.z, w2[2], base);
        base = __fmaf_rn(a.w, w2[3], base);
        base = __fmaf_rn(b.x, w2[4], base);
        base = __fmaf_rn(b.y, w2[5], base);
        base = __fmaf_rn(b.z, w2[6], base);
        base = __fmaf_rn(b.w, w2[7], base);
        base = __fmaf_rn(c8,  w2[8], base);
        int i0 = s_idx[0][t], i1 = s_idx[1][t], i2 = s_idx[2][t], i3 = s_idx[3][t];
        int i4 = s_idx[4][t], i5 = s_idx[5][t], i6 = s_idx[6][t], i7 = s_idx[7][t];
        float g0 = s_u.g[i0][o], g1 = s_u.g[i1][o], g2 = s_u.g[i2][o], g3 = s_u.g[i3][o];
        float g4 = s_u.g[i4][o], g5 = s_u.g[i5][o], g6 = s_u.g[i6][o], g7 = s_u.g[i7][o];
        float gm = fmaxf(fmaxf(fmaxf(g0, g1), fmaxf(g2, g3)),
                         fmaxf(fmaxf(g4, g5), fmaxf(g6, g7)));
        acc = fmaxf(acc, gm + base);      // base hoisted out of the k-max
    }
    s_red[w][o] = acc;
    __syncthreads();

    // ---- Phase G: cross-wave reduce, BN + leakyReLU + mask-max, store ----
    if (tid < CO) {
        float m = fmaxf(fmaxf(s_red[0][tid], s_red[1][tid]),
                        fmaxf(s_red[2][tid], s_red[3][tid]));
        float scale = bn_gamma[tid] / sqrtf(bn_var[tid] + 0.001f);
        float bias  = bn_beta[tid] - bn_mean[tid] * scale;
        float h = m * fabsf(scale) + bias;    // m tracks sgn*h_pre
        float a = (h > 0.f) ? h : 0.2f * h;   // leaky_relu
        if (nv < TPTS) a = fmaxf(a, 0.f);     // masked rows contribute 0
        out[v * CO + tid] = a;
    }
}

extern "C" void kernel_launch(void* const* d_in, const int* in_sizes, int n_in,
                              void* d_out, int out_size, void* d_ws, size_t ws_size,
                              hipStream_t stream) {
    const float* features = (const float*)d_in[0];
    const float* conv_w   = (const float*)d_in[1];
    const float* bn_gamma = (const float*)d_in[2];
    const float* bn_beta  = (const float*)d_in[3];
    const float* bn_mean  = (const float*)d_in[4];
    const float* bn_var   = (const float*)d_in[5];
    const int*   num_vox  = (const int*)d_in[6];
    const int*   coor     = (const int*)d_in[7];
    float* outp = (float*)d_out;
    const int V = in_sizes[6];   // 4096 voxels
    dgcnn_kernel<<<V, 256, 0, stream>>>(features, conv_w, bn_gamma, bn_beta,
                                        bn_mean, bn_var, num_vox, coor, outp);
}

// Round 5
// 123.049 us; speedup vs baseline: 1.5539x; 1.0086x over previous
//
#include <hip/hip_runtime.h>

#define TPTS 100   // points per voxel (T)
#define CO   64    // output channels
#define KK   8     // k-NN

// Distances: the 9-dim edge feature is an affine image of the raw point
// (x,y,z,w), so |f_t - f_s|^2 = 3dx^2 + 3dy^2 + 2dz^2 + dw^2 for valid
// rows; masked columns (f_s = 0) give e = |f_t|^2 (9-dim norm, s_xx).
// Top-8 selection uses packed keys: (as_uint(e) & ~0x7F) | s  -- uint
// order == float order (e >= 0), ties break by lowest index.
// Round-5 structure: candidate scan split across thread pair (t, t+128)
// so ALL 4 waves run identical-length code in the dominant phase (R4's
// VALUBusy=59% was SIMD imbalance: waves 2,3 idle during D).
__device__ __forceinline__ unsigned umin_(unsigned a, unsigned b) { return a < b ? a : b; }
__device__ __forceinline__ unsigned umax_(unsigned a, unsigned b) { return a > b ? a : b; }

__device__ __forceinline__ unsigned dist_key(const float4 qt, const float4 qs, unsigned s) {
    float dx = qt.x - qs.x, dy = qt.y - qs.y;
    float dz = qt.z - qs.z, dw = qt.w - qs.w;
    float e = __fmaf_rn(dx, dx, __fmaf_rn(dy, dy, __fmaf_rn(dz, dz, dw * dw)));
    return (__float_as_uint(e) & 0xFFFFFF80u) | s;
}

__global__ __launch_bounds__(256) void dgcnn_kernel(
    const float* __restrict__ features,   // [V][100][4]
    const float* __restrict__ conv_w,     // [64][18]
    const float* __restrict__ bn_gamma,
    const float* __restrict__ bn_beta,
    const float* __restrict__ bn_mean,
    const float* __restrict__ bn_var,
    const int*  __restrict__ num_voxels,  // [V]
    const int*  __restrict__ coors,       // [V][4]
    float* __restrict__ out)              // [V][64]
{
    // rows: [0..3] = scaled coords q=(sqrt3*x, sqrt3*y, sqrt2*z, w) [masked],
    //       [4..8] = f_cluster/f_center channels [masked]; scale is folded
    //       into the conv weights.
    __shared__ float s_feat[TPTS][12];    // 4800 B
    __shared__ float s_xx[TPTS];          //  400 B  9-dim |feat|^2
    __shared__ int   s_idx[KK][TPTS];     // 3200 B  keys (A-side) then final idx
    __shared__ float s_red[4][CO];        // 1024 B
    __shared__ float s_mean[4];
    __shared__ union {                    // 25600 B (time-shared)
        float stage[TPTS][4];             // raw features (A/B)
        float g[TPTS][CO];                // g[s][o] (E/F)
    } s_u;

    const float INF = __builtin_inff();
    const int v   = blockIdx.x;
    const int tid = threadIdx.x;
    const int nv  = num_voxels[v];

    // ---- Phase A: stage raw features ----
    float4 f = make_float4(0.f, 0.f, 0.f, 0.f);
    if (tid < TPTS) {
        f = reinterpret_cast<const float4*>(features)[v * TPTS + tid];
        *reinterpret_cast<float4*>(&s_u.stage[tid][0]) = f;
    }
    __syncthreads();

    // ---- Phase B: mean of ch 0..2 over ALL 100 raw rows, / nv ----
    if (tid < 96) {
        int ch = tid >> 5, j = tid & 31;
        float p = s_u.stage[j][ch] + s_u.stage[j + 32][ch] + s_u.stage[j + 64][ch];
        if (j < 4) p += s_u.stage[j + 96][ch];
        #pragma unroll
        for (int off = 16; off >= 1; off >>= 1)
            p += __shfl_xor(p, off, 32);
        if (j == 0) s_mean[ch] = p / (float)nv;
    }
    __syncthreads();

    // ---- Phase C: build masked feat rows (scaled coords inline) + xx ----
    if (tid < TPTS) {
        float mask = (tid < nv) ? 1.0f : 0.0f;
        float c3 = (float)coors[v * 4 + 3];
        float c2 = (float)coors[v * 4 + 2];
        float r0 = f.x * mask, r1 = f.y * mask, r2 = f.z * mask, r3 = f.w * mask;
        float r4 = (f.x - s_mean[0]) * mask;
        float r5 = (f.y - s_mean[1]) * mask;
        float r6 = (f.z - s_mean[2]) * mask;
        float r7 = (f.x - (c3 * 0.2f + 0.1f)) * mask;    // VX, X_OFF
        float r8 = (f.y - (c2 * 0.2f - 39.9f)) * mask;   // VY, Y_OFF
        float xx = r0*r0 + r1*r1 + r2*r2 + r3*r3 + r4*r4
                 + r5*r5 + r6*r6 + r7*r7 + r8*r8;
        float4* rowv = reinterpret_cast<float4*>(&s_feat[tid][0]);
        rowv[0] = make_float4(1.7320508075688772f * r0,
                              1.7320508075688772f * r1,
                              1.4142135623730951f * r2, r3);
        rowv[1] = make_float4(r4, r5, r6, r7);
        rowv[2] = make_float4(r8, 0.f, 0.f, 0.f);
        s_xx[tid] = xx;
    }

    // ---- weights (all threads; scale-compensated, sign-folded) ----
    const int o = tid & 63;
    const int w = tid >> 6;
    const float sgn = (bn_gamma[o] < 0.f) ? -1.f : 1.f;
    float w1[9], w2[9];
    #pragma unroll
    for (int c = 0; c < 9; ++c) {
        const float ws = (c == 0 || c == 1) ? 0.57735026918962576f
                       : (c == 2) ? 0.70710678118654752f : 1.f;
        float a = conv_w[o * 18 + c];
        float b = conv_w[o * 18 + 9 + c];
        w1[c] = a * sgn * ws;
        w2[c] = (b - a) * sgn * ws;
    }
    __syncthreads();

    // ---- Phase D: split top-8 — pair (t, t+128) scans half candidates each ----
    const int side = tid >> 7;             // 0 = A (low half), 1 = B (high + masked)
    const int t    = tid & 127;            // row (valid when < nv)
    unsigned val[KK];
    if (t < nv) {
        const float4 qt = *reinterpret_cast<const float4*>(&s_feat[t][0]);
        #pragma unroll
        for (int k = 0; k < KK; ++k) val[k] = 0xFFFFFFFFu;
        const int h  = (nv + 1) >> 1;
        const int lo = side ? h : 0;
        const int hi = side ? nv : h;
        for (int s = lo; s < hi; ++s) {
            const float4 qs = *reinterpret_cast<const float4*>(&s_feat[s][0]);
            unsigned key = dist_key(qt, qs, (unsigned)s);
            #pragma unroll
            for (int k = 0; k < KK; ++k) {   // sorted insertion (val asc)
                unsigned l = umin_(val[k], key);
                key = umax_(val[k], key);
                val[k] = l;
            }
        }
        if (side) {  // masked columns: e = |f_t|^2, indices nv, nv+1, ...
            int mcnt = TPTS - nv; if (mcnt > KK) mcnt = KK;
            unsigned kmb = __float_as_uint(s_xx[t]) & 0xFFFFFF80u;
            for (int j = 0; j < mcnt; ++j) {
                unsigned key = kmb | (unsigned)(nv + j);
                #pragma unroll
                for (int k = 0; k < KK; ++k) {
                    unsigned l = umin_(val[k], key);
                    key = umax_(val[k], key);
                    val[k] = l;
                }
            }
        } else {     // A-side publishes its sorted keys
            #pragma unroll
            for (int k = 0; k < KK; ++k) s_idx[k][t] = (int)val[k];
        }
    }
    __syncthreads();

    // ---- Phase M (B-side): bitonic half-clean merge of two sorted 8-lists ----
    if (side && t < nv) {
        unsigned a[KK];
        #pragma unroll
        for (int k = 0; k < KK; ++k) a[k] = (unsigned)s_idx[k][t];
        #pragma unroll
        for (int k = 0; k < KK; ++k)       // {min(A[k],B[7-k])} = 8 smallest of union
            s_idx[k][t] = (int)(umin_(a[k], val[KK - 1 - k]) & 127u);
    }

    // ---- Phase E (all 4 waves): g[s][o] = sgn * <feat_s, W1_o> ----
    for (int j = 0; j < 25; ++j) {
        int sR = w * 25 + j;               // wave-uniform -> broadcast reads
        const float4* row = reinterpret_cast<const float4*>(&s_feat[sR][0]);
        float4 a = row[0], b = row[1];
        float c8 = s_feat[sR][8];
        float g = a.x * w1[0];
        g = __fmaf_rn(a.y, w1[1], g);
        g = __fmaf_rn(a.z, w1[2], g);
        g = __fmaf_rn(a.w, w1[3], g);
        g = __fmaf_rn(b.x, w1[4], g);
        g = __fmaf_rn(b.y, w1[5], g);
        g = __fmaf_rn(b.z, w1[6], g);
        g = __fmaf_rn(b.w, w1[7], g);
        g = __fmaf_rn(c8,  w1[8], g);
        s_u.g[sR][o] = g;                  // lane-consecutive -> conflict-free
    }
    __syncthreads();

    // ---- Phase F: acc[o] = max over valid t of (max_k g[idx]) + base[t] ----
    float acc = -INF;
    for (int tt = w; tt < nv; tt += 4) {   // interleaved: balanced across waves
        const float4* row = reinterpret_cast<const float4*>(&s_feat[tt][0]);
        float4 a = row[0], b = row[1];
        float c8 = s_feat[tt][8];
        float base = a.x * w2[0];
        base = __fmaf_rn(a.y, w2[1], base);
        base = __fmaf_rn(a.z, w2[2], base);
        base = __fmaf_rn(a.w, w2[3], base);
        base = __fmaf_rn(b.x, w2[4], base);
        base = __fmaf_rn(b.y, w2[5], base);
        base = __fmaf_rn(b.z, w2[6], base);
        base = __fmaf_rn(b.w, w2[7], base);
        base = __fmaf_rn(c8,  w2[8], base);
        int i0 = s_idx[0][tt], i1 = s_idx[1][tt], i2 = s_idx[2][tt], i3 = s_idx[3][tt];
        int i4 = s_idx[4][tt], i5 = s_idx[5][tt], i6 = s_idx[6][tt], i7 = s_idx[7][tt];
        float g0 = s_u.g[i0][o], g1 = s_u.g[i1][o], g2 = s_u.g[i2][o], g3 = s_u.g[i3][o];
        float g4 = s_u.g[i4][o], g5 = s_u.g[i5][o], g6 = s_u.g[i6][o], g7 = s_u.g[i7][o];
        float gm = fmaxf(fmaxf(fmaxf(g0, g1), fmaxf(g2, g3)),
                         fmaxf(fmaxf(g4, g5), fmaxf(g6, g7)));
        acc = fmaxf(acc, gm + base);       // base hoisted out of the k-max
    }
    s_red[w][o] = acc;
    __syncthreads();

    // ---- Phase G: cross-wave reduce, BN + leakyReLU + mask-max, store ----
    if (tid < CO) {
        float m = fmaxf(fmaxf(s_red[0][tid], s_red[1][tid]),
                        fmaxf(s_red[2][tid], s_red[3][tid]));
        float scale = bn_gamma[tid] / sqrtf(bn_var[tid] + 0.001f);
        float bias  = bn_beta[tid] - bn_mean[tid] * scale;
        float h = m * fabsf(scale) + bias;    // m tracks sgn*h_pre
        float a = (h > 0.f) ? h : 0.2f * h;   // leaky_relu
        if (nv < TPTS) a = fmaxf(a, 0.f);     // masked rows contribute 0
        out[v * CO + tid] = a;
    }
}

extern "C" void kernel_launch(void* const* d_in, const int* in_sizes, int n_in,
                              void* d_out, int out_size, void* d_ws, size_t ws_size,
                              hipStream_t stream) {
    const float* features = (const float*)d_in[0];
    const float* conv_w   = (const float*)d_in[1];
    const float* bn_gamma = (const float*)d_in[2];
    const float* bn_beta  = (const float*)d_in[3];
    const float* bn_mean  = (const float*)d_in[4];
    const float* bn_var   = (const float*)d_in[5];
    const int*   num_vox  = (const int*)d_in[6];
    const int*   coor     = (const int*)d_in[7];
    float* outp = (float*)d_out;
    const int V = in_sizes[6];   // 4096 voxels
    dgcnn_kernel<<<V, 256, 0, stream>>>(features, conv_w, bn_gamma, bn_beta,
                                        bn_mean, bn_var, num_vox, coor, outp);
}

// Round 6
// 117.230 us; speedup vs baseline: 1.6310x; 1.0496x over previous
//
#include <hip/hip_runtime.h>

#define TPTS 100   // points per voxel (T)
#define CO   64    // output channels
#define KK   8     // k-NN

// Distances: the 9-dim edge feature is an affine image of the raw point
// (x,y,z,w), so |f_t - f_s|^2 = 3dx^2 + 3dy^2 + 2dz^2 + dw^2 for valid
// rows; masked columns (f_s = 0) give e = |f_t|^2 (9-dim norm, s_xx).
// Top-8 selection uses packed keys: (as_uint(e) & ~0x7F) | s  -- uint
// order == float order (e >= 0), ties break by lowest index.
// R6: parallel insertion (median identity: val'[k] = min(val[k],
// max(val[k-1], x)) -- bit-identical to serial insertion, depth 2 not 16),
// and Phase E restricted to s < nv with exact zero-fill of masked g rows.
__device__ __forceinline__ unsigned umin_(unsigned a, unsigned b) { return a < b ? a : b; }
__device__ __forceinline__ unsigned umax_(unsigned a, unsigned b) { return a > b ? a : b; }

__device__ __forceinline__ unsigned dist_key(const float4 qt, const float4 qs, unsigned s) {
    float dx = qt.x - qs.x, dy = qt.y - qs.y;
    float dz = qt.z - qs.z, dw = qt.w - qs.w;
    float e = __fmaf_rn(dx, dx, __fmaf_rn(dy, dy, __fmaf_rn(dz, dz, dw * dw)));
    return (__float_as_uint(e) & 0xFFFFFF80u) | s;
}

// insert key into sorted-ascending val[0..7]; all slots independent (depth 2)
__device__ __forceinline__ void ins8(unsigned val[KK], unsigned key) {
    #pragma unroll
    for (int k = KK - 1; k >= 1; --k)
        val[k] = umin_(val[k], umax_(val[k - 1], key));
    val[0] = umin_(val[0], key);
}

__global__ __launch_bounds__(256) void dgcnn_kernel(
    const float* __restrict__ features,   // [V][100][4]
    const float* __restrict__ conv_w,     // [64][18]
    const float* __restrict__ bn_gamma,
    const float* __restrict__ bn_beta,
    const float* __restrict__ bn_mean,
    const float* __restrict__ bn_var,
    const int*  __restrict__ num_voxels,  // [V]
    const int*  __restrict__ coors,       // [V][4]
    float* __restrict__ out)              // [V][64]
{
    // rows: [0..3] = scaled coords q=(sqrt3*x, sqrt3*y, sqrt2*z, w) [masked],
    //       [4..8] = f_cluster/f_center channels [masked]; scale folded into
    //       the conv weights.
    __shared__ float s_feat[TPTS][12];    // 4800 B
    __shared__ float s_xx[TPTS];          //  400 B  9-dim |feat|^2
    __shared__ int   s_idx[KK][TPTS];     // 3200 B  keys (A-side) then final idx
    __shared__ float s_red[4][CO];        // 1024 B
    __shared__ float s_mean[4];
    __shared__ union {                    // 25600 B (time-shared)
        float stage[TPTS][4];             // raw features (A/B)
        float g[TPTS][CO];                // g[s][o] (E/F)
    } s_u;

    const float INF = __builtin_inff();
    const int v   = blockIdx.x;
    const int tid = threadIdx.x;
    const int nv  = num_voxels[v];

    // ---- Phase A: stage raw features ----
    float4 f = make_float4(0.f, 0.f, 0.f, 0.f);
    if (tid < TPTS) {
        f = reinterpret_cast<const float4*>(features)[v * TPTS + tid];
        *reinterpret_cast<float4*>(&s_u.stage[tid][0]) = f;
    }
    __syncthreads();

    // ---- Phase B: mean of ch 0..2 over ALL 100 raw rows, / nv ----
    if (tid < 96) {
        int ch = tid >> 5, j = tid & 31;
        float p = s_u.stage[j][ch] + s_u.stage[j + 32][ch] + s_u.stage[j + 64][ch];
        if (j < 4) p += s_u.stage[j + 96][ch];
        #pragma unroll
        for (int off = 16; off >= 1; off >>= 1)
            p += __shfl_xor(p, off, 32);
        if (j == 0) s_mean[ch] = p / (float)nv;
    }
    __syncthreads();

    // ---- Phase C: build masked feat rows (scaled coords inline) + xx ----
    if (tid < TPTS) {
        float mask = (tid < nv) ? 1.0f : 0.0f;
        float c3 = (float)coors[v * 4 + 3];
        float c2 = (float)coors[v * 4 + 2];
        float r0 = f.x * mask, r1 = f.y * mask, r2 = f.z * mask, r3 = f.w * mask;
        float r4 = (f.x - s_mean[0]) * mask;
        float r5 = (f.y - s_mean[1]) * mask;
        float r6 = (f.z - s_mean[2]) * mask;
        float r7 = (f.x - (c3 * 0.2f + 0.1f)) * mask;    // VX, X_OFF
        float r8 = (f.y - (c2 * 0.2f - 39.9f)) * mask;   // VY, Y_OFF
        float xx = r0*r0 + r1*r1 + r2*r2 + r3*r3 + r4*r4
                 + r5*r5 + r6*r6 + r7*r7 + r8*r8;
        float4* rowv = reinterpret_cast<float4*>(&s_feat[tid][0]);
        rowv[0] = make_float4(1.7320508075688772f * r0,
                              1.7320508075688772f * r1,
                              1.4142135623730951f * r2, r3);
        rowv[1] = make_float4(r4, r5, r6, r7);
        rowv[2] = make_float4(r8, 0.f, 0.f, 0.f);
        s_xx[tid] = xx;
    }

    // ---- weights (all threads; scale-compensated, sign-folded) ----
    const int o = tid & 63;
    const int w = tid >> 6;
    const float sgn = (bn_gamma[o] < 0.f) ? -1.f : 1.f;
    float w1[9], w2[9];
    #pragma unroll
    for (int c = 0; c < 9; ++c) {
        const float ws = (c == 0 || c == 1) ? 0.57735026918962576f
                       : (c == 2) ? 0.70710678118654752f : 1.f;
        float a = conv_w[o * 18 + c];
        float b = conv_w[o * 18 + 9 + c];
        w1[c] = a * sgn * ws;
        w2[c] = (b - a) * sgn * ws;
    }
    __syncthreads();

    // ---- Phase D: split top-8 — pair (t, t+128) scans half candidates each ----
    const int side = tid >> 7;             // 0 = A (low half), 1 = B (high + masked)
    const int t    = tid & 127;            // row (valid when < nv)
    unsigned val[KK];
    if (t < nv) {
        const float4 qt = *reinterpret_cast<const float4*>(&s_feat[t][0]);
        #pragma unroll
        for (int k = 0; k < KK; ++k) val[k] = 0xFFFFFFFFu;
        const int h  = (nv + 1) >> 1;
        const int lo = side ? h : 0;
        const int hi = side ? nv : h;
        #pragma unroll 2
        for (int s = lo; s < hi; ++s) {
            const float4 qs = *reinterpret_cast<const float4*>(&s_feat[s][0]);
            ins8(val, dist_key(qt, qs, (unsigned)s));
        }
        if (side) {  // masked columns: e = |f_t|^2, indices nv, nv+1, ...
            int mcnt = TPTS - nv; if (mcnt > KK) mcnt = KK;
            unsigned kmb = __float_as_uint(s_xx[t]) & 0xFFFFFF80u;
            for (int j = 0; j < mcnt; ++j)
                ins8(val, kmb | (unsigned)(nv + j));
        } else {     // A-side publishes its sorted keys
            #pragma unroll
            for (int k = 0; k < KK; ++k) s_idx[k][t] = (int)val[k];
        }
    }
    __syncthreads();

    // ---- Phase M (B-side): bitonic half-clean merge of two sorted 8-lists ----
    if (side && t < nv) {
        unsigned a[KK];
        #pragma unroll
        for (int k = 0; k < KK; ++k) a[k] = (unsigned)s_idx[k][t];
        #pragma unroll
        for (int k = 0; k < KK; ++k)       // {min(A[k],B[7-k])} = 8 smallest of union
            s_idx[k][t] = (int)(umin_(a[k], val[KK - 1 - k]) & 127u);
    }

    // ---- zero-fill masked g rows [nv, min(nv+8,100)) — exact (+0.0) ----
    {
        int r0 = nv + w, r1 = nv + w + 4;
        if (r0 < TPTS) s_u.g[r0][o] = 0.f;   // r0 < nv+8 always (w<4)
        if (r1 < TPTS) s_u.g[r1][o] = 0.f;
    }

    // ---- Phase E (all 4 waves, valid rows only): g[s][o] = sgn*<feat_s,W1_o> ----
    for (int sR = w; sR < nv; sR += 4) {   // interleaved: balanced for any nv
        const float4* row = reinterpret_cast<const float4*>(&s_feat[sR][0]);
        float4 a = row[0], b = row[1];
        float c8 = s_feat[sR][8];
        float g = a.x * w1[0];
        g = __fmaf_rn(a.y, w1[1], g);
        g = __fmaf_rn(a.z, w1[2], g);
        g = __fmaf_rn(a.w, w1[3], g);
        g = __fmaf_rn(b.x, w1[4], g);
        g = __fmaf_rn(b.y, w1[5], g);
        g = __fmaf_rn(b.z, w1[6], g);
        g = __fmaf_rn(b.w, w1[7], g);
        g = __fmaf_rn(c8,  w1[8], g);
        s_u.g[sR][o] = g;                  // lane-consecutive -> conflict-free
    }
    __syncthreads();

    // ---- Phase F: acc[o] = max over valid t of (max_k g[idx]) + base[t] ----
    float acc = -INF;
    for (int tt = w; tt < nv; tt += 4) {   // interleaved: balanced across waves
        const float4* row = reinterpret_cast<const float4*>(&s_feat[tt][0]);
        float4 a = row[0], b = row[1];
        float c8 = s_feat[tt][8];
        float base = a.x * w2[0];
        base = __fmaf_rn(a.y, w2[1], base);
        base = __fmaf_rn(a.z, w2[2], base);
        base = __fmaf_rn(a.w, w2[3], base);
        base = __fmaf_rn(b.x, w2[4], base);
        base = __fmaf_rn(b.y, w2[5], base);
        base = __fmaf_rn(b.z, w2[6], base);
        base = __fmaf_rn(b.w, w2[7], base);
        base = __fmaf_rn(c8,  w2[8], base);
        int i0 = s_idx[0][tt], i1 = s_idx[1][tt], i2 = s_idx[2][tt], i3 = s_idx[3][tt];
        int i4 = s_idx[4][tt], i5 = s_idx[5][tt], i6 = s_idx[6][tt], i7 = s_idx[7][tt];
        float g0 = s_u.g[i0][o], g1 = s_u.g[i1][o], g2 = s_u.g[i2][o], g3 = s_u.g[i3][o];
        float g4 = s_u.g[i4][o], g5 = s_u.g[i5][o], g6 = s_u.g[i6][o], g7 = s_u.g[i7][o];
        float gm = fmaxf(fmaxf(fmaxf(g0, g1), fmaxf(g2, g3)),
                         fmaxf(fmaxf(g4, g5), fmaxf(g6, g7)));
        acc = fmaxf(acc, gm + base);       // base hoisted out of the k-max
    }
    s_red[w][o] = acc;
    __syncthreads();

    // ---- Phase G: cross-wave reduce, BN + leakyReLU + mask-max, store ----
    if (tid < CO) {
        float m = fmaxf(fmaxf(s_red[0][tid], s_red[1][tid]),
                        fmaxf(s_red[2][tid], s_red[3][tid]));
        float scale = bn_gamma[tid] / sqrtf(bn_var[tid] + 0.001f);
        float bias  = bn_beta[tid] - bn_mean[tid] * scale;
        float h = m * fabsf(scale) + bias;    // m tracks sgn*h_pre
        float a = (h > 0.f) ? h : 0.2f * h;   // leaky_relu
        if (nv < TPTS) a = fmaxf(a, 0.f);     // masked rows contribute 0
        out[v * CO + tid] = a;
    }
}

extern "C" void kernel_launch(void* const* d_in, const int* in_sizes, int n_in,
                              void* d_out, int out_size, void* d_ws, size_t ws_size,
                              hipStream_t stream) {
    const float* features = (const float*)d_in[0];
    const float* conv_w   = (const float*)d_in[1];
    const float* bn_gamma = (const float*)d_in[2];
    const float* bn_beta  = (const float*)d_in[3];
    const float* bn_mean  = (const float*)d_in[4];
    const float* bn_var   = (const float*)d_in[5];
    const int*   num_vox  = (const int*)d_in[6];
    const int*   coor     = (const int*)d_in[7];
    float* outp = (float*)d_out;
    const int V = in_sizes[6];   // 4096 voxels
    dgcnn_kernel<<<V, 256, 0, stream>>>(features, conv_w, bn_gamma, bn_beta,
                                        bn_mean, bn_var, num_vox, coor, outp);
}